// Round 1
// baseline (437.095 us; speedup 1.0000x reference)
//
#include <hip/hip_runtime.h>
#include <math.h>

#define D 512
#define H 500
#define NSPAN 256
#define KCON 1024
#define L 64
#define NEG_INF -1e30f
#define RCHUNK 8
#define GRIDY 2

// ---------------- Kernel 1: sentinel = relu(span @ Ws + bs) ----------------
__global__ __launch_bounds__(512) void k_sentinel(
    const float* __restrict__ span, const float* __restrict__ Ws,
    const float* __restrict__ bs, float* __restrict__ sentinel) {
    __shared__ float x[D];
    int n = blockIdx.x;
    int j = threadIdx.x;  // 512 threads, one output column each
    x[j] = span[n * D + j];
    __syncthreads();
    float a0 = 0.f, a1 = 0.f, a2 = 0.f, a3 = 0.f;
    for (int k = 0; k < D; k += 4) {
        a0 = fmaf(x[k + 0], Ws[(k + 0) * D + j], a0);
        a1 = fmaf(x[k + 1], Ws[(k + 1) * D + j], a1);
        a2 = fmaf(x[k + 2], Ws[(k + 2) * D + j], a2);
        a3 = fmaf(x[k + 3], Ws[(k + 3) * D + j], a3);
    }
    float acc = ((a0 + a1) + (a2 + a3)) + bs[j];
    sentinel[n * D + j] = fmaxf(acc, 0.f);
}

// ------- Kernel 2: span_part / know_part / sent_part (x @ W1half) ----------
__global__ __launch_bounds__(512) void k_parts(
    const float* __restrict__ span, const float* __restrict__ know,
    const float* __restrict__ sentinel, const float* __restrict__ W1,
    float* __restrict__ span_part, float* __restrict__ know_part,
    float* __restrict__ sent_part) {
    __shared__ float x[D];
    int b = blockIdx.x;
    int j = threadIdx.x;  // 512 threads; j < H produce output
    const float* xr;
    const float* Wb;
    float* out;
    if (b < NSPAN) {
        xr = span + b * D; Wb = W1; out = span_part + b * H;
    } else if (b < NSPAN + KCON) {
        int r = b - NSPAN;
        xr = know + r * D; Wb = W1 + D * H; out = know_part + r * H;
    } else {
        int r = b - NSPAN - KCON;
        xr = sentinel + r * D; Wb = W1 + D * H; out = sent_part + r * H;
    }
    x[j] = xr[j];
    __syncthreads();
    if (j < H) {
        float a0 = 0.f, a1 = 0.f, a2 = 0.f, a3 = 0.f;
        for (int k = 0; k < D; k += 4) {
            a0 = fmaf(x[k + 0], Wb[(k + 0) * H + j], a0);
            a1 = fmaf(x[k + 1], Wb[(k + 1) * H + j], a1);
            a2 = fmaf(x[k + 2], Wb[(k + 2) * H + j], a2);
            a3 = fmaf(x[k + 3], Wb[(k + 3) * H + j], a3);
        }
        out[j] = (a0 + a1) + (a2 + a3);
    }
}

// ---- Kernel 3: scores for ACTIVE positions only (gather-then-compute) -----
// Active rows for span n: l = 0..V-1 (concepts, V = max(len,1)) plus sentinel
// (stored at l = L). h1 = relu(span_part + part + b1); h2 = relu(h1@W2 + b2);
// score = h2 . W3 + b3.
__global__ __launch_bounds__(512) void k_scores(
    const int* __restrict__ s2c, const int* __restrict__ lengths,
    const float* __restrict__ span_part, const float* __restrict__ know_part,
    const float* __restrict__ sent_part, const float* __restrict__ b1,
    const float* __restrict__ W2, const float* __restrict__ b2,
    const float* __restrict__ W3, const float* __restrict__ b3,
    float* __restrict__ scores) {
    int n = blockIdx.x;
    int j = threadIdx.x;  // 512 threads, col j < H
    int V = lengths[n];
    if (V < 1) V = 1;
    int R = V + 1;  // active rows incl. sentinel

    __shared__ float h1[RCHUNK][H];
    __shared__ float red[RCHUNK][8];

    float sp = 0.f, b1j = 0.f, b2j = 0.f, w3j = 0.f;
    if (j < H) {
        sp = span_part[n * H + j];
        b1j = b1[j];
        b2j = b2[j];
        w3j = W3[j];
    }
    float b3v = b3[0];
    int lane = j & 63, wv = j >> 6;

    for (int r0 = blockIdx.y * RCHUNK; r0 < R; r0 += RCHUNK * GRIDY) {
        int rc = min(RCHUNK, R - r0);
        // build h1 rows for this chunk
        if (j < H) {
            for (int r = 0; r < rc; ++r) {
                int row = r0 + r;
                float kp;
                if (row < V) {
                    int c = s2c[n * L + row];
                    kp = know_part[c * H + j];
                } else {
                    kp = sent_part[n * H + j];
                }
                h1[r][j] = fmaxf(sp + kp + b1j, 0.f);
            }
        }
        __syncthreads();
        // h2 column j for all chunk rows; W2 read coalesced, h1 broadcast
        float acc[RCHUNK];
#pragma unroll
        for (int r = 0; r < RCHUNK; ++r) acc[r] = 0.f;
        if (j < H) {
#pragma unroll 2
            for (int k = 0; k < H; ++k) {
                float w = W2[k * H + j];
#pragma unroll
                for (int r = 0; r < RCHUNK; ++r) acc[r] = fmaf(h1[r][k], w, acc[r]);
            }
        }
        __syncthreads();  // h1 reads done before next-iter overwrite
        // per-row dot with W3: wave reduce then cross-wave reduce
        for (int r = 0; r < rc; ++r) {
            float v = (j < H) ? fmaxf(acc[r] + b2j, 0.f) * w3j : 0.f;
#pragma unroll
            for (int off = 32; off > 0; off >>= 1) v += __shfl_down(v, off, 64);
            if (lane == 0) red[r][wv] = v;
        }
        __syncthreads();
        if (j < rc) {
            float s = 0.f;
#pragma unroll
            for (int w = 0; w < 8; ++w) s += red[j][w];
            int row = r0 + j;
            int l = (row < V) ? row : L;
            scores[n * (L + 1) + l] = s + b3v;
        }
        __syncthreads();  // red reads done before next-iter overwrite
    }
}

// -------- Kernel 4: masked softmax + probs out + feature gather ------------
__global__ __launch_bounds__(512) void k_out(
    const int* __restrict__ s2c, const int* __restrict__ lengths,
    const float* __restrict__ scores, const float* __restrict__ know,
    const float* __restrict__ sentinel, float* __restrict__ out_features,
    float* __restrict__ out_probs) {
    int n = blockIdx.x;
    int j = threadIdx.x;  // 512 threads
    __shared__ float p[L + 1];
    __shared__ int idx[L];
    int V = lengths[n];
    if (V < 1) V = 1;
    if (j < L) idx[j] = s2c[n * L + j];
    if (j == 0) {
        const float* srow = scores + n * (L + 1);
        float m = srow[L];  // sentinel always valid
        for (int l = 0; l < V; ++l) m = fmaxf(m, srow[l]);
        float sum = 0.f;
        for (int l = 0; l <= L; ++l) {
            float e = 0.f;
            if (l < V || l == L) e = expf(srow[l] - m);
            p[l] = e;
            sum += e;
        }
        float inv = 1.f / sum;
        for (int l = 0; l <= L; ++l) p[l] *= inv;
    }
    __syncthreads();
    if (j <= L) out_probs[n * (L + 1) + j] = p[j];
    float acc = p[L] * sentinel[n * D + j];
    for (int l = 0; l < V; ++l) acc = fmaf(p[l], know[idx[l] * D + j], acc);
    out_features[n * D + j] = acc;
}

extern "C" void kernel_launch(void* const* d_in, const int* in_sizes, int n_in,
                              void* d_out, int out_size, void* d_ws, size_t ws_size,
                              hipStream_t stream) {
    const float* span = (const float*)d_in[0];   // (256, 512)
    const float* know = (const float*)d_in[1];   // (1024, 512)
    const int* s2c = (const int*)d_in[2];        // (256, 64)
    const int* lengths = (const int*)d_in[3];    // (256,)
    const float* Ws = (const float*)d_in[4];     // (512, 512)
    const float* bs = (const float*)d_in[5];     // (512,)
    const float* W1 = (const float*)d_in[6];     // (1024, 500)
    const float* b1 = (const float*)d_in[7];     // (500,)
    const float* W2 = (const float*)d_in[8];     // (500, 500)
    const float* b2 = (const float*)d_in[9];     // (500,)
    const float* W3 = (const float*)d_in[10];    // (500, 1)
    const float* b3 = (const float*)d_in[11];    // (1,)

    float* ws = (float*)d_ws;
    float* sentinel = ws;                       // 256*512
    float* span_part = sentinel + NSPAN * D;    // 256*500
    float* know_part = span_part + NSPAN * H;   // 1024*500
    float* sent_part = know_part + KCON * H;    // 256*500
    float* scores = sent_part + NSPAN * H;      // 256*65

    float* out_features = (float*)d_out;             // 256*512
    float* out_probs = out_features + NSPAN * D;     // 256*65

    k_sentinel<<<NSPAN, 512, 0, stream>>>(span, Ws, bs, sentinel);
    k_parts<<<NSPAN + KCON + NSPAN, 512, 0, stream>>>(
        span, know, sentinel, W1, span_part, know_part, sent_part);
    k_scores<<<dim3(NSPAN, GRIDY), 512, 0, stream>>>(
        s2c, lengths, span_part, know_part, sent_part, b1, W2, b2, W3, b3, scores);
    k_out<<<NSPAN, 512, 0, stream>>>(s2c, lengths, scores, know, sentinel,
                                     out_features, out_probs);
}

// Round 2
// 322.420 us; speedup vs baseline: 1.3557x; 1.3557x over previous
//
#include <hip/hip_runtime.h>
#include <math.h>

#define D 512
#define H 500
#define HV4 125           // H/4 exact: 500 = 125 float4
#define NSPAN 256
#define KCON 1024
#define L 64
#define RT 16             // rows per k_scores block
#define NCHUNK 5          // ceil(65/16)
#define HPAD 20           // htile row pad (floats): 80B rows keep q*16 16B-aligned

// ---------------- Kernel 1: sentinel = relu(span @ Ws + bs) ----------------
// 4 rows/block; thread = (c: 128 col-groups of 4) x (q: 4 rows)
__global__ __launch_bounds__(512) void k_sentinel(
    const float* __restrict__ span, const float* __restrict__ Ws,
    const float* __restrict__ bs, float* __restrict__ sentinel) {
    __shared__ __align__(16) float xt[D][5];
    int n0 = blockIdx.x * 4;
    int tid = threadIdx.x;
    int j = tid;
    #pragma unroll
    for (int r = 0; r < 4; ++r) xt[j][r] = span[(n0 + r) * D + j];
    __syncthreads();
    int c = tid & 127, q = tid >> 7;
    const float4* Wv = reinterpret_cast<const float4*>(Ws) + c;  // row stride 128
    float a0 = 0.f, a1 = 0.f, a2 = 0.f, a3 = 0.f;
    float4 w = Wv[0];
    float h = xt[0][q];
    #pragma unroll 4
    for (int k = 0; k < D; ++k) {
        int kn = (k + 1 < D) ? (k + 1) : (D - 1);
        float4 wn = Wv[kn * 128];
        float hn = xt[kn][q];
        a0 = fmaf(h, w.x, a0); a1 = fmaf(h, w.y, a1);
        a2 = fmaf(h, w.z, a2); a3 = fmaf(h, w.w, a3);
        w = wn; h = hn;
    }
    float4 b = reinterpret_cast<const float4*>(bs)[c];
    float4 o;
    o.x = fmaxf(a0 + b.x, 0.f); o.y = fmaxf(a1 + b.y, 0.f);
    o.z = fmaxf(a2 + b.z, 0.f); o.w = fmaxf(a3 + b.w, 0.f);
    *reinterpret_cast<float4*>(&sentinel[(n0 + q) * D + c * 4]) = o;
}

// ------- Kernel 2: span_part / know_part / sent_part (x @ W1half) ----------
// 8 rows/block (192 blocks); thread = (c: 125 col-groups of 4) x (q: 4 groups of 2 rows)
__global__ __launch_bounds__(512) void k_parts(
    const float* __restrict__ span, const float* __restrict__ know,
    const float* __restrict__ sentinel, const float* __restrict__ W1,
    float* __restrict__ span_part, float* __restrict__ know_part,
    float* __restrict__ sent_part) {
    __shared__ __align__(16) float xt[D][10];
    int b = blockIdx.x;
    int tid = threadIdx.x;
    const float* xbase;
    const float* Wb;
    float* out;
    if (b < 32) {                 // spans
        xbase = span + b * 8 * D; Wb = W1; out = span_part + b * 8 * H;
    } else if (b < 160) {         // knowledge
        int r = b * 8 - NSPAN;
        xbase = know + r * D; Wb = W1 + D * H; out = know_part + r * H;
    } else {                      // sentinels
        int r = b * 8 - NSPAN - KCON;
        xbase = sentinel + r * D; Wb = W1 + D * H; out = sent_part + r * H;
    }
    int j = tid;
    #pragma unroll
    for (int r = 0; r < 8; ++r) xt[j][r] = xbase[r * D + j];
    __syncthreads();
    int c = tid & 127, q = tid >> 7;
    if (c >= HV4) return;
    const float4* Wv = reinterpret_cast<const float4*>(Wb) + c;  // row stride 125
    float acc[2][4];
    #pragma unroll
    for (int r = 0; r < 2; ++r)
        #pragma unroll
        for (int x = 0; x < 4; ++x) acc[r][x] = 0.f;
    float4 w = Wv[0];
    float2 h = *reinterpret_cast<const float2*>(&xt[0][q * 2]);
    #pragma unroll 4
    for (int k = 0; k < D; ++k) {
        int kn = (k + 1 < D) ? (k + 1) : (D - 1);
        float4 wn = Wv[kn * HV4];
        float2 hn = *reinterpret_cast<const float2*>(&xt[kn][q * 2]);
        acc[0][0] = fmaf(h.x, w.x, acc[0][0]); acc[0][1] = fmaf(h.x, w.y, acc[0][1]);
        acc[0][2] = fmaf(h.x, w.z, acc[0][2]); acc[0][3] = fmaf(h.x, w.w, acc[0][3]);
        acc[1][0] = fmaf(h.y, w.x, acc[1][0]); acc[1][1] = fmaf(h.y, w.y, acc[1][1]);
        acc[1][2] = fmaf(h.y, w.z, acc[1][2]); acc[1][3] = fmaf(h.y, w.w, acc[1][3]);
        w = wn; h = hn;
    }
    #pragma unroll
    for (int r = 0; r < 2; ++r) {
        float4 o; o.x = acc[r][0]; o.y = acc[r][1]; o.z = acc[r][2]; o.w = acc[r][3];
        *reinterpret_cast<float4*>(&out[(q * 2 + r) * H + c * 4]) = o;
    }
}

// ---- Kernel 3: scores for ACTIVE positions only, 16-row chunks ----
// grid (span, chunk). h1 tile transposed in LDS: htile[k][row], row pad 20.
// thread = (c: 125 col-groups of 4) x (q: 4 groups of 4 rows).
__global__ __launch_bounds__(512) void k_scores(
    const int* __restrict__ s2c, const int* __restrict__ lengths,
    const float* __restrict__ span_part, const float* __restrict__ know_part,
    const float* __restrict__ sent_part, const float* __restrict__ b1,
    const float* __restrict__ W2, const float* __restrict__ b2,
    const float* __restrict__ W3, const float* __restrict__ b3,
    float* __restrict__ scores) {
    int n = blockIdx.x;
    int V = lengths[n];
    if (V < 1) V = 1;
    int R = V + 1;
    int r0 = blockIdx.y * RT;
    if (r0 >= R) return;
    int rc = min(RT, R - r0);

    __shared__ __align__(16) float htile[H][HPAD];  // 40000 B
    __shared__ float red[8][4];

    int tid = threadIdx.x;
    int j = tid;
    if (j < H) {
        float sp = span_part[n * H + j];
        float b1j = b1[j];
        #pragma unroll
        for (int r = 0; r < RT; ++r) {
            float v = 0.f;
            if (r < rc) {
                int row = r0 + r;
                float kp;
                if (row < V) kp = know_part[s2c[n * L + row] * H + j];
                else kp = sent_part[n * H + j];
                v = fmaxf(sp + kp + b1j, 0.f);
            }
            htile[j][r] = v;
        }
    }
    __syncthreads();

    int c = tid & 127, q = tid >> 7;
    float acc[4][4];
    #pragma unroll
    for (int r = 0; r < 4; ++r)
        #pragma unroll
        for (int x = 0; x < 4; ++x) acc[r][x] = 0.f;

    float vr[4] = {0.f, 0.f, 0.f, 0.f};
    if (c < HV4) {
        const float4* W2v = reinterpret_cast<const float4*>(W2) + c;  // row stride 125
        float4 w = W2v[0];
        float4 h = *reinterpret_cast<const float4*>(&htile[0][q * 4]);
        #pragma unroll 2
        for (int k = 0; k < H; ++k) {
            int kn = (k + 1 < H) ? (k + 1) : (H - 1);
            float4 wn = W2v[kn * HV4];
            float4 hn = *reinterpret_cast<const float4*>(&htile[kn][q * 4]);
            acc[0][0] = fmaf(h.x, w.x, acc[0][0]); acc[0][1] = fmaf(h.x, w.y, acc[0][1]);
            acc[0][2] = fmaf(h.x, w.z, acc[0][2]); acc[0][3] = fmaf(h.x, w.w, acc[0][3]);
            acc[1][0] = fmaf(h.y, w.x, acc[1][0]); acc[1][1] = fmaf(h.y, w.y, acc[1][1]);
            acc[1][2] = fmaf(h.y, w.z, acc[1][2]); acc[1][3] = fmaf(h.y, w.w, acc[1][3]);
            acc[2][0] = fmaf(h.z, w.x, acc[2][0]); acc[2][1] = fmaf(h.z, w.y, acc[2][1]);
            acc[2][2] = fmaf(h.z, w.z, acc[2][2]); acc[2][3] = fmaf(h.z, w.w, acc[2][3]);
            acc[3][0] = fmaf(h.w, w.x, acc[3][0]); acc[3][1] = fmaf(h.w, w.y, acc[3][1]);
            acc[3][2] = fmaf(h.w, w.z, acc[3][2]); acc[3][3] = fmaf(h.w, w.w, acc[3][3]);
            w = wn; h = hn;
        }
        // epilogue: relu(acc + b2) . W3 partials
        float4 b2v = reinterpret_cast<const float4*>(b2)[c];
        float4 w3v = reinterpret_cast<const float4*>(W3)[c];
        #pragma unroll
        for (int r = 0; r < 4; ++r) {
            vr[r] = fmaxf(acc[r][0] + b2v.x, 0.f) * w3v.x
                  + fmaxf(acc[r][1] + b2v.y, 0.f) * w3v.y
                  + fmaxf(acc[r][2] + b2v.z, 0.f) * w3v.z
                  + fmaxf(acc[r][3] + b2v.w, 0.f) * w3v.w;
        }
    }
    // wave reduce (all lanes of a wave share q -> same 4 rows)
    #pragma unroll
    for (int r = 0; r < 4; ++r) {
        float v = vr[r];
        #pragma unroll
        for (int off = 32; off > 0; off >>= 1) v += __shfl_down(v, off, 64);
        vr[r] = v;
    }
    int wv = tid >> 6, lane = tid & 63;
    if (lane == 0) {
        #pragma unroll
        for (int r = 0; r < 4; ++r) red[wv][r] = vr[r];
    }
    __syncthreads();
    if (tid < RT && tid < rc) {
        int row = tid;
        int qq = row >> 2, rr = row & 3;
        float s = red[qq * 2][rr] + red[qq * 2 + 1][rr] + b3[0];
        int ar = r0 + row;
        int l = (ar < V) ? ar : L;
        scores[n * (L + 1) + l] = s;
    }
}

// -------- Kernel 4: masked softmax + probs out + feature gather ------------
__global__ __launch_bounds__(512) void k_out(
    const int* __restrict__ s2c, const int* __restrict__ lengths,
    const float* __restrict__ scores, const float* __restrict__ know,
    const float* __restrict__ sentinel, float* __restrict__ out_features,
    float* __restrict__ out_probs) {
    int n = blockIdx.x;
    int j = threadIdx.x;
    __shared__ float p[L + 1];
    __shared__ int idx[L];
    int V = lengths[n];
    if (V < 1) V = 1;
    if (j < L) idx[j] = s2c[n * L + j];
    if (j == 0) {
        const float* srow = scores + n * (L + 1);
        float m = srow[L];
        for (int l = 0; l < V; ++l) m = fmaxf(m, srow[l]);
        float sum = 0.f;
        for (int l = 0; l <= L; ++l) {
            float e = 0.f;
            if (l < V || l == L) e = expf(srow[l] - m);
            p[l] = e;
            sum += e;
        }
        float inv = 1.f / sum;
        for (int l = 0; l <= L; ++l) p[l] *= inv;
    }
    __syncthreads();
    if (j <= L) out_probs[n * (L + 1) + j] = p[j];
    float acc = p[L] * sentinel[n * D + j];
    for (int l = 0; l < V; ++l) acc = fmaf(p[l], know[idx[l] * D + j], acc);
    out_features[n * D + j] = acc;
}

extern "C" void kernel_launch(void* const* d_in, const int* in_sizes, int n_in,
                              void* d_out, int out_size, void* d_ws, size_t ws_size,
                              hipStream_t stream) {
    const float* span = (const float*)d_in[0];   // (256, 512)
    const float* know = (const float*)d_in[1];   // (1024, 512)
    const int* s2c = (const int*)d_in[2];        // (256, 64)
    const int* lengths = (const int*)d_in[3];    // (256,)
    const float* Ws = (const float*)d_in[4];     // (512, 512)
    const float* bs = (const float*)d_in[5];     // (512,)
    const float* W1 = (const float*)d_in[6];     // (1024, 500)
    const float* b1 = (const float*)d_in[7];     // (500,)
    const float* W2 = (const float*)d_in[8];     // (500, 500)
    const float* b2 = (const float*)d_in[9];     // (500,)
    const float* W3 = (const float*)d_in[10];    // (500, 1)
    const float* b3 = (const float*)d_in[11];    // (1,)

    float* ws = (float*)d_ws;
    float* sentinel = ws;                       // 256*512
    float* span_part = sentinel + NSPAN * D;    // 256*500
    float* know_part = span_part + NSPAN * H;   // 1024*500
    float* sent_part = know_part + KCON * H;    // 256*500
    float* scores = sent_part + NSPAN * H;      // 256*65

    float* out_features = (float*)d_out;             // 256*512
    float* out_probs = out_features + NSPAN * D;     // 256*65

    k_sentinel<<<NSPAN / 4, 512, 0, stream>>>(span, Ws, bs, sentinel);
    k_parts<<<(NSPAN + KCON + NSPAN) / 8, 512, 0, stream>>>(
        span, know, sentinel, W1, span_part, know_part, sent_part);
    k_scores<<<dim3(NSPAN, NCHUNK), 512, 0, stream>>>(
        s2c, lengths, span_part, know_part, sent_part, b1, W2, b2, W3, b3, scores);
    k_out<<<NSPAN, 512, 0, stream>>>(s2c, lengths, scores, know, sentinel,
                                     out_features, out_probs);
}

// Round 3
// 263.281 us; speedup vs baseline: 1.6602x; 1.2246x over previous
//
#include <hip/hip_runtime.h>
#include <math.h>

#define D 512
#define H 500
#define HV4 125           // H/4
#define NSPAN 256
#define KCON 1024
#define L 64
#define RT 16             // rows per k_scores block
#define NCHUNK 5          // ceil(65/16)
#define HP 504            // ht row stride in floats (504%4==0 -> 16B aligned rows)

// Pipelined GEMM core: each thread computes NR rows x 4 cols over K = NG*4,
// with A/B double-buffered register groups (8 float4 global loads in flight).
// Wv: weight matrix as float4 rows of WS4 groups; hbase: this thread's first
// input row (floats, stride hstride); c: float4 column group.
template <int NG, int WS4, int NR>
__device__ __forceinline__ void gemm_rows(const float4* __restrict__ Wv,
                                          const float* __restrict__ hbase,
                                          int hstride, int c, float4* acc) {
    float4 wa[4], wb[4], ha[NR], hb[NR];
    auto loadg = [&](float4* w, float4* h, int g) {
        int k4 = g * 4;
        #pragma unroll
        for (int i = 0; i < 4; ++i) w[i] = Wv[(k4 + i) * WS4 + c];
        #pragma unroll
        for (int r = 0; r < NR; ++r)
            h[r] = *(const float4*)(hbase + r * hstride + k4);
    };
    auto comp = [&](const float4* w, const float4* h) {
        #pragma unroll
        for (int r = 0; r < NR; ++r) {
            float4 a = acc[r];
            a.x = fmaf(h[r].x, w[0].x, a.x); a.y = fmaf(h[r].x, w[0].y, a.y);
            a.z = fmaf(h[r].x, w[0].z, a.z); a.w = fmaf(h[r].x, w[0].w, a.w);
            a.x = fmaf(h[r].y, w[1].x, a.x); a.y = fmaf(h[r].y, w[1].y, a.y);
            a.z = fmaf(h[r].y, w[1].z, a.z); a.w = fmaf(h[r].y, w[1].w, a.w);
            a.x = fmaf(h[r].z, w[2].x, a.x); a.y = fmaf(h[r].z, w[2].y, a.y);
            a.z = fmaf(h[r].z, w[2].z, a.z); a.w = fmaf(h[r].z, w[2].w, a.w);
            a.x = fmaf(h[r].w, w[3].x, a.x); a.y = fmaf(h[r].w, w[3].y, a.y);
            a.z = fmaf(h[r].w, w[3].z, a.z); a.w = fmaf(h[r].w, w[3].w, a.w);
            acc[r] = a;
        }
    };
    loadg(wa, ha, 0);
    int g = 0;
    for (; g + 2 < NG; g += 2) {
        loadg(wb, hb, g + 1);
        comp(wa, ha);
        loadg(wa, ha, g + 2);
        comp(wb, hb);
    }
    if (NG % 2 == 0) {          // constexpr-folded
        loadg(wb, hb, NG - 1);
        comp(wa, ha);
        comp(wb, hb);
    } else {
        comp(wa, ha);
    }
}

// ------- Kernel 1: fused sentinel + span/know/sent W1-halves GEMMs ---------
// 192 blocks x 8 rows. b<32: span@W1a; b<160: know@W1b; b>=160: sentinel rows
// (relu(span@Ws+bs) -> ws + restage -> @W1b). Thread = (c:128)x(q:4, 2 rows).
__global__ __launch_bounds__(512, 4) void k_parts(
    const float* __restrict__ span, const float* __restrict__ know,
    const float* __restrict__ Ws, const float* __restrict__ bs,
    const float* __restrict__ W1,
    float* __restrict__ sentinel, float* __restrict__ span_part,
    float* __restrict__ know_part, float* __restrict__ sent_part) {
    __shared__ __align__(16) float xt[8][D];
    int b = blockIdx.x, tid = threadIdx.x;
    int c = tid & 127, q = tid >> 7;

    const float* xbase;
    if (b < 32) xbase = span + b * 8 * D;
    else if (b < 160) xbase = know + (b - 32) * 8 * D;
    else xbase = span + (b - 160) * 8 * D;
    #pragma unroll
    for (int r = 0; r < 8; ++r) xt[r][tid] = xbase[r * D + tid];
    __syncthreads();

    if (b < 160) {
        if (c < HV4) {
            const float* Wb = (b < 32) ? W1 : (W1 + D * H);
            float* out = (b < 32) ? (span_part + b * 8 * H)
                                  : (know_part + (b - 32) * 8 * H);
            float4 acc[2] = {};
            gemm_rows<D / 4, HV4, 2>((const float4*)Wb, &xt[2 * q][0], D, c, acc);
            *(float4*)&out[(2 * q + 0) * H + 4 * c] = acc[0];
            *(float4*)&out[(2 * q + 1) * H + 4 * c] = acc[1];
        }
        return;
    }
    // sentinel blocks: GEMM1 = relu(span @ Ws + bs)
    int r0 = (b - 160) * 8;
    float4 acc[2] = {};
    gemm_rows<D / 4, D / 4, 2>((const float4*)Ws, &xt[2 * q][0], D, c, acc);
    float4 bv = ((const float4*)bs)[c];
    acc[0].x = fmaxf(acc[0].x + bv.x, 0.f); acc[0].y = fmaxf(acc[0].y + bv.y, 0.f);
    acc[0].z = fmaxf(acc[0].z + bv.z, 0.f); acc[0].w = fmaxf(acc[0].w + bv.w, 0.f);
    acc[1].x = fmaxf(acc[1].x + bv.x, 0.f); acc[1].y = fmaxf(acc[1].y + bv.y, 0.f);
    acc[1].z = fmaxf(acc[1].z + bv.z, 0.f); acc[1].w = fmaxf(acc[1].w + bv.w, 0.f);
    *(float4*)&sentinel[(r0 + 2 * q + 0) * D + 4 * c] = acc[0];
    *(float4*)&sentinel[(r0 + 2 * q + 1) * D + 4 * c] = acc[1];
    __syncthreads();                       // xt reads of GEMM1 done
    *(float4*)&xt[2 * q + 0][4 * c] = acc[0];
    *(float4*)&xt[2 * q + 1][4 * c] = acc[1];
    __syncthreads();
    if (c < HV4) {
        float4 a2[2] = {};
        gemm_rows<D / 4, HV4, 2>((const float4*)(W1 + D * H), &xt[2 * q][0], D, c, a2);
        *(float4*)&sent_part[(r0 + 2 * q + 0) * H + 4 * c] = a2[0];
        *(float4*)&sent_part[(r0 + 2 * q + 1) * H + 4 * c] = a2[1];
    }
}

// ---- Kernel 2: scores for ACTIVE positions, 16-row chunks, pipelined ------
// ht transposed [row][k]: writes lane-consecutive (conflict-free), reads are
// wave-uniform float4 broadcasts. Thread = (c:125)x(q:4, 4-row quad).
__global__ __launch_bounds__(512, 4) void k_scores(
    const int* __restrict__ s2c, const int* __restrict__ lengths,
    const float* __restrict__ span_part, const float* __restrict__ know_part,
    const float* __restrict__ sent_part, const float* __restrict__ b1,
    const float* __restrict__ W2, const float* __restrict__ b2,
    const float* __restrict__ W3, const float* __restrict__ b3,
    float* __restrict__ scores) {
    int n = blockIdx.x;
    int V = lengths[n];
    if (V < 1) V = 1;
    int R = V + 1;
    int r0 = blockIdx.y * RT;
    if (r0 >= R) return;
    int rc = min(RT, R - r0);

    __shared__ __align__(16) float ht[RT][HP];   // 32256 B
    __shared__ float red[8][4];

    int tid = threadIdx.x;
    if (tid < H) {
        int j = tid;
        float sb = span_part[n * H + j] + b1[j];
        #pragma unroll
        for (int r = 0; r < RT; ++r) {
            int row = r0 + r;
            int ci = s2c[n * L + min(row, V - 1)];
            const float* src = (row < V) ? (know_part + ci * H) : (sent_part + n * H);
            ht[r][j] = (r < rc) ? fmaxf(sb + src[j], 0.f) : 0.f;
        }
    }
    __syncthreads();

    int c = tid & 127;
    int q4 = (tid >> 7) * 4;
    float vr[4] = {0.f, 0.f, 0.f, 0.f};
    if (c < HV4 && q4 < rc) {   // skip waves whose whole quad is past rc
        float4 acc[4] = {};
        gemm_rows<HV4, HV4, 4>((const float4*)W2, &ht[q4][0], HP, c, acc);
        float4 b2v = ((const float4*)b2)[c];
        float4 w3v = ((const float4*)W3)[c];
        #pragma unroll
        for (int r = 0; r < 4; ++r) {
            vr[r] = fmaxf(acc[r].x + b2v.x, 0.f) * w3v.x
                  + fmaxf(acc[r].y + b2v.y, 0.f) * w3v.y
                  + fmaxf(acc[r].z + b2v.z, 0.f) * w3v.z
                  + fmaxf(acc[r].w + b2v.w, 0.f) * w3v.w;
        }
    }
    #pragma unroll
    for (int r = 0; r < 4; ++r) {
        float v = vr[r];
        #pragma unroll
        for (int off = 32; off > 0; off >>= 1) v += __shfl_down(v, off, 64);
        vr[r] = v;
    }
    int wv = tid >> 6, lane = tid & 63;
    if (lane == 0) {
        #pragma unroll
        for (int r = 0; r < 4; ++r) red[wv][r] = vr[r];
    }
    __syncthreads();
    if (tid < rc) {
        int qq = tid >> 2, rr = tid & 3;
        float s = red[qq * 2][rr] + red[qq * 2 + 1][rr] + b3[0];
        int ar = r0 + tid;
        int lpos = (ar < V) ? ar : L;
        scores[n * (L + 1) + lpos] = s;
    }
}

// -------- Kernel 3: masked softmax + probs out + feature gather ------------
__global__ __launch_bounds__(512) void k_out(
    const int* __restrict__ s2c, const int* __restrict__ lengths,
    const float* __restrict__ scores, const float* __restrict__ know,
    const float* __restrict__ sentinel, float* __restrict__ out_features,
    float* __restrict__ out_probs) {
    int n = blockIdx.x;
    int j = threadIdx.x;
    __shared__ float p[L + 1];
    __shared__ int idx[L];
    int V = lengths[n];
    if (V < 1) V = 1;
    if (j < L) idx[j] = s2c[n * L + j];
    if (j == 0) {
        const float* srow = scores + n * (L + 1);
        float m = srow[L];
        for (int l = 0; l < V; ++l) m = fmaxf(m, srow[l]);
        float sum = 0.f;
        for (int l = 0; l < V; ++l) { float e = expf(srow[l] - m); p[l] = e; sum += e; }
        for (int l = V; l < L; ++l) p[l] = 0.f;
        float es = expf(srow[L] - m); p[L] = es; sum += es;
        float inv = 1.f / sum;
        for (int l = 0; l <= L; ++l) p[l] *= inv;
    }
    __syncthreads();
    if (j <= L) out_probs[n * (L + 1) + j] = p[j];
    float acc = p[L] * sentinel[n * D + j];
    int l = 0;
    for (; l + 4 <= V; l += 4) {
        float p0 = p[l], p1 = p[l + 1], p2 = p[l + 2], p3 = p[l + 3];
        float v0 = know[idx[l] * D + j];
        float v1 = know[idx[l + 1] * D + j];
        float v2 = know[idx[l + 2] * D + j];
        float v3 = know[idx[l + 3] * D + j];
        acc = fmaf(p0, v0, acc); acc = fmaf(p1, v1, acc);
        acc = fmaf(p2, v2, acc); acc = fmaf(p3, v3, acc);
    }
    for (; l < V; ++l) acc = fmaf(p[l], know[idx[l] * D + j], acc);
    out_features[n * D + j] = acc;
}

extern "C" void kernel_launch(void* const* d_in, const int* in_sizes, int n_in,
                              void* d_out, int out_size, void* d_ws, size_t ws_size,
                              hipStream_t stream) {
    const float* span = (const float*)d_in[0];   // (256, 512)
    const float* know = (const float*)d_in[1];   // (1024, 512)
    const int* s2c = (const int*)d_in[2];        // (256, 64)
    const int* lengths = (const int*)d_in[3];    // (256,)
    const float* Ws = (const float*)d_in[4];     // (512, 512)
    const float* bs = (const float*)d_in[5];     // (512,)
    const float* W1 = (const float*)d_in[6];     // (1024, 500)
    const float* b1 = (const float*)d_in[7];     // (500,)
    const float* W2 = (const float*)d_in[8];     // (500, 500)
    const float* b2 = (const float*)d_in[9];     // (500,)
    const float* W3 = (const float*)d_in[10];    // (500, 1)
    const float* b3 = (const float*)d_in[11];    // (1,)

    float* ws = (float*)d_ws;
    float* sentinel = ws;                       // 256*512
    float* span_part = sentinel + NSPAN * D;    // 256*500
    float* know_part = span_part + NSPAN * H;   // 1024*500
    float* sent_part = know_part + KCON * H;    // 256*500
    float* scores = sent_part + NSPAN * H;      // 256*65

    float* out_features = (float*)d_out;             // 256*512
    float* out_probs = out_features + NSPAN * D;     // 256*65

    k_parts<<<192, 512, 0, stream>>>(span, know, Ws, bs, W1, sentinel,
                                     span_part, know_part, sent_part);
    k_scores<<<dim3(NSPAN, NCHUNK), 512, 0, stream>>>(
        s2c, lengths, span_part, know_part, sent_part, b1, W2, b2, W3, b3, scores);
    k_out<<<NSPAN, 512, 0, stream>>>(s2c, lengths, scores, know, sentinel,
                                     out_features, out_probs);
}